// Round 4
// baseline (185.916 us; speedup 1.0000x reference)
//
#include <hip/hip_runtime.h>
#include <hip/hip_bf16.h>
#include <math.h>

#define NN 512
#define VN 40
#define NF 32
#define EFD 4
#define OUTD 128
#define EMAX 96     // max directed edges per graph (<= 90 actual)
#define DMAX 8      // max in-degree
#define MSTR 136    // LDS row stride (shorts) for 128-wide MFMA A-operands
#define WPSTR 104   // row stride (shorts) for 96-wide (68-padded) operands
#define NT 512      // k_mp threads (8 waves): __launch_bounds__(512,4) -> VGPR cap 128, 2 blocks/CU
#define NW 8
#define EPW 12      // edges per wave (EMAX/NW)

typedef __attribute__((ext_vector_type(8))) short short8;
typedef __attribute__((ext_vector_type(4))) float f32x4;

// tanh(x) = 1 - 2/(exp(2x)+1)
__device__ __forceinline__ float fast_tanh(float x) {
    return fmaf(-2.0f, __builtin_amdgcn_rcpf(__expf(2.0f * x) + 1.0f), 1.0f);
}
__device__ __forceinline__ unsigned bf16b(float x) {
    __hip_bfloat16 h = __float2bfloat16(x);
    unsigned short u;
    __builtin_memcpy(&u, &h, 2);
    return (unsigned)u;
}
__device__ __forceinline__ unsigned packbf(float lo, float hi) {
    return (bf16b(hi) << 16) | bf16b(lo);
}

// Setup: [0,nbO): off boundaries | [nbO,+nbK): eoff boundaries | [+128): weight conv
__global__ __launch_bounds__(256) void k_setup(
    const int* __restrict__ igeb, const int* __restrict__ eb_b,
    const float* __restrict__ W_att, const float* __restrict__ W_emb,
    const float* __restrict__ Wg_att, const float* __restrict__ Wg_emb,
    const float* __restrict__ W_pre,
    int* __restrict__ off, int* __restrict__ eoff,
    __hip_bfloat16* __restrict__ Wt1, __hip_bfloat16* __restrict__ Wt2,
    __hip_bfloat16* __restrict__ Wt3, __hip_bfloat16* __restrict__ Wpt,
    int K, int E, int nbO, int nbK)
{
    int bid = blockIdx.x, tid = threadIdx.x;
    if (bid < nbO) {                       // per-graph edge offsets (eb_b sorted)
        int e = bid * 256 + tid;
        if (e >= E) return;
        int b = eb_b[e];
        if (e == 0) { for (int bb = 0; bb <= b; ++bb) off[bb] = 0; }
        else { int pb = eb_b[e - 1]; for (int bb = pb + 1; bb <= b; ++bb) off[bb] = e; }
        if (e == E - 1) { for (int bb = b + 1; bb <= NN; ++bb) off[bb] = E; }
        return;
    }
    bid -= nbO;
    if (bid < nbK) {                       // per-edge K-offsets (igeb sorted)
        int k = bid * 256 + tid;
        if (k >= K) return;
        int e = igeb[k];
        if (k == 0) { for (int ee = 0; ee <= e; ++ee) eoff[ee] = 0; }
        else { int pe = igeb[k - 1]; for (int ee = pe + 1; ee <= e; ++ee) eoff[ee] = k; }
        if (k == K - 1) { for (int ee = e + 1; ee <= E; ++ee) eoff[ee] = K; }
        return;
    }
    bid -= nbK;
    // weight transpose/convert (2 output-cols per block)
    int c = bid * 2 + (tid >> 7), k = tid & 127;
    int cc = c & 127; bool hi = c >= 128;
    if (!hi) {                             // emb-top half only (att-top cancels in softmax)
        Wt1[c * 128 + k] = __float2bfloat16(W_emb[k * 128 + c]);
        if (k < WPSTR)
            Wpt[c * WPSTR + k] = __float2bfloat16(k < 68 ? W_pre[k * 128 + c] : 0.f);
    }
    Wt2[c * 128 + k] = __float2bfloat16(hi ? W_emb[(128 + k) * 128 + cc] : W_att[(128 + k) * 128 + cc]);
    Wt3[c * 128 + k] = __float2bfloat16(hi ? Wg_emb[k * 128 + cc]
                                           : (Wg_att[k * 128 + cc] + Wg_att[(128 + k) * 128 + cc]));
}

// Fully-fused per-graph pre + MP + readout. 512 threads (8 waves), ~80 KB LDS, 2 blocks/CU.
__global__ __launch_bounds__(NT, 4) void k_mp(
    const float* __restrict__ nodes, const float* __restrict__ edges,
    const __hip_bfloat16* __restrict__ Wpt, const float* __restrict__ b_pre,
    const __hip_bfloat16* __restrict__ Wt1, const float* __restrict__ b_emb,
    const __hip_bfloat16* __restrict__ Wt2, const __hip_bfloat16* __restrict__ Wt3,
    const float* __restrict__ bg_att, const float* __restrict__ bg_emb,
    const int* __restrict__ igeb, const int* __restrict__ ieb,
    const int* __restrict__ eoff,
    const int* __restrict__ eb_n, const int* __restrict__ eb_nb,
    const float* __restrict__ node_mask,
    const float* __restrict__ W_out, const float* __restrict__ b_out,
    const int* __restrict__ off, float* __restrict__ out)
{
    __shared__ __align__(16) char pool[75264];
    __shared__ float gembL[128];
    __shared__ float nmL[VN];
    __shared__ int srcL[EMAX * DMAX];    // compacted LOCAL source indices
    __shared__ int degL[EMAX];           // per-edge in-degree
    __shared__ int nodeL[EMAX];
    __shared__ int nbL[EMAX];
    // Phase-aliased pool regions (all transitions barrier-separated):
    __hip_bfloat16* eIn  = (__hip_bfloat16*)(pool + 26112);   // [96][WPSTR] prologue only
    __hip_bfloat16* eL   = (__hip_bfloat16*)pool;             // [96][MSTR]  e_emb
    __hip_bfloat16* beL  = (__hip_bfloat16*)(pool + 26112);   // [96][128]   exp(2*be) (over dead eIn)
    const unsigned short* beLu = (const unsigned short*)(pool + 26112);
    __hip_bfloat16* memL = (__hip_bfloat16*)pool;             // [96][MSTR]  (over dead eL, written AFTER P3 barrier)
    unsigned*       MaMeL = (unsigned*)(pool + 26112);        // [96][128] lo=bf16(exp(Ma)) hi=bf16(exp(2Me))
    float*          nsF   = (float*)pool;                     // [40][128] (over memL after Mae step1)
    __hip_bfloat16* nsbL  = (__hip_bfloat16*)(pool + 26112);  // [48][MSTR]
    unsigned*       GOLp  = (unsigned*)(pool + 39168);        // [48][128] packed exp
    float*          numP  = (float*)pool;                     // [NT] (post-GO, over memL)
    float*          denP  = (float*)(pool + 2048);            // [NT]
    float*          redL  = (float*)(pool + 4096);            // [NT]

    int b = blockIdx.x;
    int s0 = off[b], s1 = off[b + 1];
    int nE = s1 - s0;
    int tid = threadIdx.x;
    int wave = tid >> 6, lane = tid & 63, lm = lane & 15, lq = lane >> 4;

    // ---- P1a: per-edge meta, edge features, pad cols; node mask ----
    if (tid < EMAX) {
        degL[tid] = 0;
        bool vld = tid < nE;
        int n = 0, nb = 0;
        if (vld) { n = eb_n[s0 + tid]; nb = eb_nb[s0 + tid]; }
        nodeL[tid] = n; nbL[tid] = nb;
        float4 ev = make_float4(0.f, 0.f, 0.f, 0.f);
        if (vld) ev = *(const float4*)&edges[(((size_t)b * VN + n) * VN + nb) * EFD];
        unsigned* dst = (unsigned*)&eIn[tid * WPSTR + 64];   // byte off tid*208+128, 16B aligned
        dst[0] = packbf(ev.x, ev.y);
        dst[1] = packbf(ev.z, ev.w);
        #pragma unroll
        for (int f = 0; f < 14; ++f) dst[2 + f] = 0u;        // shorts 68..96 zero (K=96 for P2)
    }
    if (tid < VN) nmL[tid] = node_mask[b * VN + tid];
    __syncthreads();
    // ---- P1b: node-feature slot gather (96 edges x 16 float4 slots) + compact in-edge scatter ----
    for (int idx = tid; idx < EMAX * 16; idx += NT) {
        int le = idx >> 4, seg = idx & 15;
        float4 v4 = make_float4(0.f, 0.f, 0.f, 0.f);
        if (le < nE) {
            int node = (seg < 8) ? nodeL[le] : nbL[le];
            v4 = *(const float4*)&nodes[((size_t)b * VN + node) * NF + (seg & 7) * 4];
        }
        unsigned* dst = (unsigned*)&eIn[le * WPSTR + ((seg < 8) ? 0 : 32) + (seg & 7) * 4];
        dst[0] = packbf(v4.x, v4.y);
        dst[1] = packbf(v4.z, v4.w);
    }
    {
        int k0 = eoff[s0], k1 = eoff[s1];
        for (int k = k0 + tid; k < k1; k += NT) {
            int le = igeb[k] - s0;
            int pos = atomicAdd(&degL[le], 1);   // order-independent sum downstream
            srcL[le * DMAX + pos] = ieb[k] - s0;
        }
    }
    __syncthreads();
    // ---- P2: e_emb = tanh(e_in @ Wpt + b_pre); col-tile c = wave, hoisted B-frags ----
    {
        int c = wave;
        short8 Bf[3];
        #pragma unroll
        for (int kb = 0; kb < 3; ++kb)
            Bf[kb] = *(const short8*)((const short*)Wpt + (size_t)(c * 16 + lm) * WPSTR + kb * 32 + lq * 8);
        float bp = b_pre[c * 16 + lm];
        int col = c * 16 + lm;
        for (int r = 0; r < 6; ++r) {
            short8 Af[3];
            #pragma unroll
            for (int kb = 0; kb < 3; ++kb)
                Af[kb] = *(const short8*)((const short*)eIn + (r * 16 + lm) * WPSTR + kb * 32 + lq * 8);
            f32x4 acc = {0.f, 0.f, 0.f, 0.f};
            #pragma unroll
            for (int kb = 0; kb < 3; ++kb)
                acc = __builtin_amdgcn_mfma_f32_16x16x32_bf16(Af[kb], Bf[kb], acc, 0, 0, 0);
            #pragma unroll
            for (int i = 0; i < 4; ++i)
                eL[(r * 16 + lq * 4 + i) * MSTR + col] = __float2bfloat16(fast_tanh(acc[i] + bp));
        }
    }
    __syncthreads();
    // ---- P3: e2b = exp(2*(e_emb @ Wt1 + b_emb)); write beL; carry tanh in regs ----
    // (memL aliases eL -> must NOT write it until all waves finish reading eL; see R3 race)
    unsigned tnh[12];
    {
        int c = wave;
        short8 Bf[4];
        #pragma unroll
        for (int kb = 0; kb < 4; ++kb)
            Bf[kb] = *(const short8*)((const short*)Wt1 + (size_t)(c * 16 + lm) * 128 + kb * 32 + lq * 8);
        float bv = b_emb[c * 16 + lm];
        int col = c * 16 + lm;
        for (int r = 0; r < 6; ++r) {
            short8 Af[4];
            #pragma unroll
            for (int kb = 0; kb < 4; ++kb)
                Af[kb] = *(const short8*)((const short*)eL + (r * 16 + lm) * MSTR + kb * 32 + lq * 8);
            f32x4 acc = {0.f, 0.f, 0.f, 0.f};
            #pragma unroll
            for (int kb = 0; kb < 4; ++kb)
                acc = __builtin_amdgcn_mfma_f32_16x16x32_bf16(Af[kb], Bf[kb], acc, 0, 0, 0);
            #pragma unroll
            for (int i = 0; i < 4; ++i) {
                int row = r * 16 + lq * 4 + i;
                float e2 = __expf(2.f * (acc[i] + bv));
                beL[row * 128 + col] = __float2bfloat16(e2);
                unsigned tb = bf16b(fmaf(-2.f, __builtin_amdgcn_rcpf(e2 + 1.f), 1.f));
                if (i & 1) tnh[r * 2 + (i >> 1)] |= tb << 16;
                else       tnh[r * 2 + (i >> 1)]  = tb;
            }
        }
    }
    __syncthreads();
    // ---- P4: eL now dead -> write memL (step-0 mem) from regs; hoist per-edge e2b ----
    {
        int col = wave * 16 + lm;
        #pragma unroll
        for (int r = 0; r < 6; ++r)
            #pragma unroll
            for (int i = 0; i < 4; ++i) {
                int row = r * 16 + lq * 4 + i;
                unsigned pk = tnh[r * 2 + (i >> 1)];
                ((unsigned short*)memL)[row * MSTR + col] =
                    (unsigned short)((i & 1) ? (pk >> 16) : (pk & 0xFFFFu));
            }
    }
    unsigned e2bP[EPW];
    #pragma unroll
    for (int i = 0; i < EPW; ++i) {
        int le = wave + i * NW;
        unsigned lo = beLu[le * 128 + lane];
        unsigned hi = beLu[le * 128 + 64 + lane];
        e2bP[i] = (hi << 16) | lo;
    }
    __syncthreads();

    // Mae B-frags (att + emb col-tile c = wave) hoisted across BOTH steps
    short8 BfA[4], BfE[4];
    {
        int c = wave;
        #pragma unroll
        for (int kb = 0; kb < 4; ++kb) {
            BfA[kb] = *(const short8*)((const short*)Wt2 + (size_t)(c * 16 + lm) * 128 + kb * 32 + lq * 8);
            BfE[kb] = *(const short8*)((const short*)Wt2 + (size_t)(128 + c * 16 + lm) * 128 + kb * 32 + lq * 8);
        }
    }

    for (int step = 0; step < 2; ++step) {
        // Mae: paired att/emb tiles sharing A-frags; packed u32 epilogue writes
        {
            int col = wave * 16 + lm;
            for (int r = 0; r < 6; ++r) {
                short8 Af[4];
                #pragma unroll
                for (int kb = 0; kb < 4; ++kb)
                    Af[kb] = *(const short8*)((const short*)memL + (r * 16 + lm) * MSTR + kb * 32 + lq * 8);
                f32x4 aa = {0.f, 0.f, 0.f, 0.f};
                #pragma unroll
                for (int kb = 0; kb < 4; ++kb)
                    aa = __builtin_amdgcn_mfma_f32_16x16x32_bf16(Af[kb], BfA[kb], aa, 0, 0, 0);
                f32x4 ae = {0.f, 0.f, 0.f, 0.f};
                #pragma unroll
                for (int kb = 0; kb < 4; ++kb)
                    ae = __builtin_amdgcn_mfma_f32_16x16x32_bf16(Af[kb], BfE[kb], ae, 0, 0, 0);
                int row0 = r * 16 + lq * 4;
                #pragma unroll
                for (int i = 0; i < 4; ++i)
                    MaMeL[(row0 + i) * 128 + col] =
                        (bf16b(__expf(2.f * ae[i])) << 16) | bf16b(__expf(aa[i]));
            }
        }
        __syncthreads();
        if (step == 1) {       // memL dead; zero nsF (same LDS) before scatter
            for (int idx = tid; idx < VN * 128; idx += NT) nsF[idx] = 0.f;
            __syncthreads();
        }
        // msg: wave-per-edge; compacted deg loop; e2b from regs (no global reads)
        #pragma unroll
        for (int i = 0; i < EPW; ++i) {
            int le = wave + i * NW;
            if (le < nE) {
                int deg = __builtin_amdgcn_readfirstlane(degL[le]);
                int sv = srcL[le * DMAX + (lane & 7)];
                unsigned pkb = e2bP[i];
                float e2b0 = __uint_as_float(pkb << 16);
                float e2b1 = __uint_as_float(pkb & 0xFFFF0000u);
                float sw0 = 0.f, swr0 = 0.f, sw1 = 0.f, swr1 = 0.f;
                for (int d = 0; d < deg; ++d) {
                    int ls = __builtin_amdgcn_readlane(sv, d);
                    unsigned pk0 = MaMeL[ls * 128 + lane];
                    unsigned pk1 = MaMeL[ls * 128 + 64 + lane];
                    float w0 = __uint_as_float(pk0 << 16);
                    float m0 = __uint_as_float(pk0 & 0xFFFF0000u);
                    float w1 = __uint_as_float(pk1 << 16);
                    float m1 = __uint_as_float(pk1 & 0xFFFF0000u);
                    sw0 += w0;
                    swr0 = fmaf(w0, __builtin_amdgcn_rcpf(fmaf(e2b0, m0, 1.f)), swr0);
                    sw1 += w1;
                    swr1 = fmaf(w1, __builtin_amdgcn_rcpf(fmaf(e2b1, m1, 1.f)), swr1);
                }
                float r0 = deg ? swr0 * __builtin_amdgcn_rcpf(sw0)
                               : __builtin_amdgcn_rcpf(e2b0 + 1.f);
                float r1 = deg ? swr1 * __builtin_amdgcn_rcpf(sw1)
                               : __builtin_amdgcn_rcpf(e2b1 + 1.f);
                float v0 = fmaf(-2.f, r0, 1.f);
                float v1 = fmaf(-2.f, r1, 1.f);
                if (step == 0) {
                    memL[le * MSTR + lane] = __float2bfloat16(v0);
                    memL[le * MSTR + 64 + lane] = __float2bfloat16(v1);
                } else {       // final step: scatter straight into node sums
                    int v = __builtin_amdgcn_readfirstlane(nodeL[le]);
                    atomicAdd(&nsF[v * 128 + lane], v0);
                    atomicAdd(&nsF[v * 128 + 64 + lane], v1);
                }
            }
        }
        __syncthreads();
    }

    // nsF -> bf16 nsbL (pads zero), packed u32 writes
    for (int idx = tid; idx < 48 * 64; idx += NT) {
        int v = idx >> 6, kp = idx & 63;
        unsigned pk = 0;
        if (v < VN) pk = packbf(nsF[v * 128 + kp * 2], nsF[v * 128 + kp * 2 + 1]);
        *(unsigned*)((unsigned short*)nsbL + v * MSTR + kp * 2) = pk;
    }
    __syncthreads();
    // GO = nsb @ Wt3 + bias : 2 col-tiles per wave, hoisted B-frags
    {
        int c0 = wave * 2, c1 = wave * 2 + 1;
        short8 Bg0[4], Bg1[4];
        #pragma unroll
        for (int kb = 0; kb < 4; ++kb) {
            Bg0[kb] = *(const short8*)((const short*)Wt3 + (size_t)(c0 * 16 + lm) * 128 + kb * 32 + lq * 8);
            Bg1[kb] = *(const short8*)((const short*)Wt3 + (size_t)(c1 * 16 + lm) * 128 + kb * 32 + lq * 8);
        }
        int col0 = c0 * 16 + lm, col1 = c1 * 16 + lm;
        float bv0 = (col0 < 128) ? bg_att[col0] : bg_emb[col0 & 127];
        float bv1 = (col1 < 128) ? bg_att[col1] : bg_emb[col1 & 127];
        __hip_bfloat16* hp = (__hip_bfloat16*)GOLp;
        for (int r = 0; r < 3; ++r) {
            short8 Af[4];
            #pragma unroll
            for (int kb = 0; kb < 4; ++kb)
                Af[kb] = *(const short8*)((const short*)nsbL + (r * 16 + lm) * MSTR + kb * 32 + lq * 8);
            f32x4 a0 = {0.f, 0.f, 0.f, 0.f}, a1 = {0.f, 0.f, 0.f, 0.f};
            #pragma unroll
            for (int kb = 0; kb < 4; ++kb) {
                a0 = __builtin_amdgcn_mfma_f32_16x16x32_bf16(Af[kb], Bg0[kb], a0, 0, 0, 0);
                a1 = __builtin_amdgcn_mfma_f32_16x16x32_bf16(Af[kb], Bg1[kb], a1, 0, 0, 0);
            }
            int row0 = r * 16 + lq * 4;
            #pragma unroll
            for (int i = 0; i < 4; ++i) {
                if (col0 < 128)
                    hp[((row0 + i) * 128 + col0) * 2] = __float2bfloat16(__expf(a0[i] + bv0));
                else
                    hp[((row0 + i) * 128 + (col0 & 127)) * 2 + 1] = __float2bfloat16(__expf(2.f * (a0[i] + bv0)));
                if (col1 < 128)
                    hp[((row0 + i) * 128 + col1) * 2] = __float2bfloat16(__expf(a1[i] + bv1));
                else
                    hp[((row0 + i) * 128 + (col1 & 127)) * 2 + 1] = __float2bfloat16(__expf(2.f * (a1[i] + bv1)));
            }
        }
    }
    __syncthreads();
    // node softmax: 4-way v-split; gemb = 1 - 2*Σ(w*r)/Σw
    {
        int c = tid & 127, q = tid >> 7;      // q in 0..3
        float sw = 0.f, swr = 0.f;
        for (int v = q; v < VN; v += 4) {
            if (nmL[v] == 0.f) continue;
            unsigned pk = GOLp[v * 128 + c];
            float w = __uint_as_float(pk << 16);
            float e2 = __uint_as_float(pk & 0xFFFF0000u);
            sw += w;
            swr = fmaf(w, __builtin_amdgcn_rcpf(e2 + 1.f), swr);
        }
        numP[tid] = swr;
        denP[tid] = sw;
    }
    __syncthreads();
    if (tid < 128) {
        float swr = 0.f, sw = 0.f;
        #pragma unroll
        for (int p = 0; p < 4; ++p) { swr += numP[p * 128 + tid]; sw += denP[p * 128 + tid]; }
        gembL[tid] = fmaf(-2.f, swr / sw, 1.f);
    }
    __syncthreads();
    // out = gemb @ W_out + b_out (4-way j-split)
    {
        int c = tid & 127, h = tid >> 7;      // h in 0..3
        float acc = 0.f;
        for (int j = h; j < 128; j += 4)
            acc += gembL[j] * W_out[j * OUTD + c];
        redL[tid] = acc;
    }
    __syncthreads();
    if (tid < 128) {
        float acc = b_out[tid];
        #pragma unroll
        for (int p = 0; p < 4; ++p) acc += redL[p * 128 + tid];
        out[(size_t)b * OUTD + tid] = acc;
    }
}

extern "C" void kernel_launch(void* const* d_in, const int* in_sizes, int n_in,
                              void* d_out, int out_size, void* d_ws, size_t ws_size,
                              hipStream_t stream) {
    const float* nodes    = (const float*)d_in[0];
    const float* edges    = (const float*)d_in[1];
    const float* W_pre    = (const float*)d_in[2];
    const float* b_pre    = (const float*)d_in[3];
    const float* W_att    = (const float*)d_in[4];
    const float* W_emb    = (const float*)d_in[6];
    const float* b_emb    = (const float*)d_in[7];
    const float* Wg_att   = (const float*)d_in[8];
    const float* bg_att   = (const float*)d_in[9];
    const float* Wg_emb   = (const float*)d_in[10];
    const float* bg_emb   = (const float*)d_in[11];
    const float* W_out    = (const float*)d_in[12];
    const float* b_out    = (const float*)d_in[13];
    const float* node_mask = (const float*)d_in[15];
    const int* eb_b   = (const int*)d_in[16];
    const int* eb_n   = (const int*)d_in[17];
    const int* eb_nb  = (const int*)d_in[18];
    const int* in_eb  = (const int*)d_in[19];
    const int* in_igeb = (const int*)d_in[20];

    int E = in_sizes[16];
    int K = in_sizes[19];

    __hip_bfloat16* Wt1 = (__hip_bfloat16*)d_ws;              // 128*128
    __hip_bfloat16* Wt2 = Wt1 + 128 * 128;                    // 256*128
    __hip_bfloat16* Wt3 = Wt2 + 256 * 128;                    // 256*128
    __hip_bfloat16* Wpt = Wt3 + 256 * 128;                    // 128*WPSTR
    int* off  = (int*)(Wpt + 128 * WPSTR);                    // NN+1
    int* eoff = off + (NN + 1);                               // E+1

    int nbO = (E + 255) / 256;
    int nbK = (K + 255) / 256;

    k_setup<<<nbO + nbK + 128, 256, 0, stream>>>(in_igeb, eb_b,
                                                 W_att, W_emb, Wg_att, Wg_emb, W_pre,
                                                 off, eoff, Wt1, Wt2, Wt3, Wpt,
                                                 K, E, nbO, nbK);
    k_mp<<<NN, NT, 0, stream>>>(nodes, edges, Wpt, b_pre, Wt1, b_emb,
                                Wt2, Wt3, bg_att, bg_emb,
                                in_igeb, in_eb, eoff, eb_n, eb_nb, node_mask,
                                W_out, b_out, off, (float*)d_out);
}

// Round 5
// 177.027 us; speedup vs baseline: 1.0502x; 1.0502x over previous
//
#include <hip/hip_runtime.h>
#include <hip/hip_bf16.h>
#include <math.h>

#define NN 512
#define VN 40
#define NF 32
#define EFD 4
#define OUTD 128
#define EMAX 96     // max directed edges per graph (<= 90 actual)
#define DMAX 8      // max in-degree
#define MSTR 136    // LDS row stride (shorts) for 128-wide MFMA A-operands
#define WPSTR 104   // row stride (shorts) for 96-wide (68-padded) operands
#define NT 512      // k_mp threads (8 waves): __launch_bounds__(512,4) -> VGPR cap 128, 2 blocks/CU
#define NW 8
#define EPW 12      // edges per wave (EMAX/NW)

typedef __attribute__((ext_vector_type(8))) short short8;
typedef __attribute__((ext_vector_type(4))) float f32x4;

// tanh(x) = 1 - 2/(exp(2x)+1)
__device__ __forceinline__ float fast_tanh(float x) {
    return fmaf(-2.0f, __builtin_amdgcn_rcpf(__expf(2.0f * x) + 1.0f), 1.0f);
}
__device__ __forceinline__ unsigned bf16b(float x) {
    __hip_bfloat16 h = __float2bfloat16(x);
    unsigned short u;
    __builtin_memcpy(&u, &h, 2);
    return (unsigned)u;
}
__device__ __forceinline__ unsigned packbf(float lo, float hi) {
    return (bf16b(hi) << 16) | bf16b(lo);
}

// Setup: [0,nbO): off boundaries | [nbO,+nbK): eoff boundaries | [+128): weight conv
__global__ __launch_bounds__(256) void k_setup(
    const int* __restrict__ igeb, const int* __restrict__ eb_b,
    const float* __restrict__ W_att, const float* __restrict__ W_emb,
    const float* __restrict__ Wg_att, const float* __restrict__ Wg_emb,
    const float* __restrict__ W_pre,
    int* __restrict__ off, int* __restrict__ eoff,
    __hip_bfloat16* __restrict__ Wt1, __hip_bfloat16* __restrict__ Wt2,
    __hip_bfloat16* __restrict__ Wt3, __hip_bfloat16* __restrict__ Wpt,
    int K, int E, int nbO, int nbK)
{
    int bid = blockIdx.x, tid = threadIdx.x;
    if (bid < nbO) {                       // per-graph edge offsets (eb_b sorted)
        int e = bid * 256 + tid;
        if (e >= E) return;
        int b = eb_b[e];
        if (e == 0) { for (int bb = 0; bb <= b; ++bb) off[bb] = 0; }
        else { int pb = eb_b[e - 1]; for (int bb = pb + 1; bb <= b; ++bb) off[bb] = e; }
        if (e == E - 1) { for (int bb = b + 1; bb <= NN; ++bb) off[bb] = E; }
        return;
    }
    bid -= nbO;
    if (bid < nbK) {                       // per-edge K-offsets (igeb sorted)
        int k = bid * 256 + tid;
        if (k >= K) return;
        int e = igeb[k];
        if (k == 0) { for (int ee = 0; ee <= e; ++ee) eoff[ee] = 0; }
        else { int pe = igeb[k - 1]; for (int ee = pe + 1; ee <= e; ++ee) eoff[ee] = k; }
        if (k == K - 1) { for (int ee = e + 1; ee <= E; ++ee) eoff[ee] = K; }
        return;
    }
    bid -= nbK;
    // weight transpose/convert (2 output-cols per block)
    int c = bid * 2 + (tid >> 7), k = tid & 127;
    int cc = c & 127; bool hi = c >= 128;
    if (!hi) {                             // emb-top half only (att-top cancels in softmax)
        Wt1[c * 128 + k] = __float2bfloat16(W_emb[k * 128 + c]);
        if (k < WPSTR)
            Wpt[c * WPSTR + k] = __float2bfloat16(k < 68 ? W_pre[k * 128 + c] : 0.f);
    }
    Wt2[c * 128 + k] = __float2bfloat16(hi ? W_emb[(128 + k) * 128 + cc] : W_att[(128 + k) * 128 + cc]);
    Wt3[c * 128 + k] = __float2bfloat16(hi ? Wg_emb[k * 128 + cc]
                                           : (Wg_att[k * 128 + cc] + Wg_att[(128 + k) * 128 + cc]));
}

// Fully-fused per-graph pre + MP + readout. 512 threads (8 waves), ~80 KB LDS, 2 blocks/CU.
// Register discipline (R4 lesson): every hoisted B-fragment set must die at its
// phase barrier — nothing hoisted may live across the msg loop, or we spill.
__global__ __launch_bounds__(NT, 4) void k_mp(
    const float* __restrict__ nodes, const float* __restrict__ edges,
    const __hip_bfloat16* __restrict__ Wpt, const float* __restrict__ b_pre,
    const __hip_bfloat16* __restrict__ Wt1, const float* __restrict__ b_emb,
    const __hip_bfloat16* __restrict__ Wt2, const __hip_bfloat16* __restrict__ Wt3,
    const float* __restrict__ bg_att, const float* __restrict__ bg_emb,
    const int* __restrict__ igeb, const int* __restrict__ ieb,
    const int* __restrict__ eoff,
    const int* __restrict__ eb_n, const int* __restrict__ eb_nb,
    const float* __restrict__ node_mask,
    const float* __restrict__ W_out, const float* __restrict__ b_out,
    const int* __restrict__ off, float* __restrict__ out)
{
    __shared__ __align__(16) char pool[75264];
    __shared__ float gembL[128];
    __shared__ float nmL[VN];
    __shared__ int srcL[EMAX * DMAX];    // compacted LOCAL source indices
    __shared__ int degL[EMAX];           // per-edge in-degree
    __shared__ int nodeL[EMAX];
    __shared__ int nbL[EMAX];
    // Phase-aliased pool regions (all transitions barrier-separated):
    __hip_bfloat16* eIn  = (__hip_bfloat16*)(pool + 26112);   // [96][WPSTR] prologue only
    __hip_bfloat16* eL   = (__hip_bfloat16*)pool;             // [96][MSTR]  e_emb
    __hip_bfloat16* beL  = (__hip_bfloat16*)(pool + 26112);   // [96][128]   exp(2*be) (over dead eIn)
    const unsigned short* beLu = (const unsigned short*)(pool + 26112);
    const unsigned* beLw = (const unsigned*)(pool + 26112);   // paired view
    __hip_bfloat16* memL = (__hip_bfloat16*)pool;             // [96][MSTR]  (over dead eL, written AFTER P3 barrier)
    unsigned*       MaMeL = (unsigned*)(pool + 26112);        // [96][128] lo=bf16(exp(Ma)) hi=bf16(exp(2Me))
    float*          nsF   = (float*)pool;                     // [40][128] (over memL after Mae step1)
    __hip_bfloat16* nsbL  = (__hip_bfloat16*)(pool + 26112);  // [48][MSTR]
    unsigned*       GOLp  = (unsigned*)(pool + 39168);        // [48][128] packed exp
    float*          numP  = (float*)pool;                     // [NT] (post-GO, over memL)
    float*          denP  = (float*)(pool + 2048);            // [NT]
    float*          redL  = (float*)(pool + 4096);            // [NT]

    int b = blockIdx.x;
    int s0 = off[b], s1 = off[b + 1];
    int nE = s1 - s0;
    int tid = threadIdx.x;
    int wave = tid >> 6, lane = tid & 63, lm = lane & 15, lq = lane >> 4;

    // ---- P1a: per-edge meta, edge features, pad cols; node mask ----
    if (tid < EMAX) {
        degL[tid] = 0;
        bool vld = tid < nE;
        int n = 0, nb = 0;
        if (vld) { n = eb_n[s0 + tid]; nb = eb_nb[s0 + tid]; }
        nodeL[tid] = n; nbL[tid] = nb;
        float4 ev = make_float4(0.f, 0.f, 0.f, 0.f);
        if (vld) ev = *(const float4*)&edges[(((size_t)b * VN + n) * VN + nb) * EFD];
        unsigned* dst = (unsigned*)&eIn[tid * WPSTR + 64];   // byte off tid*208+128, 16B aligned
        dst[0] = packbf(ev.x, ev.y);
        dst[1] = packbf(ev.z, ev.w);
        #pragma unroll
        for (int f = 0; f < 14; ++f) dst[2 + f] = 0u;        // shorts 68..96 zero (K=96 for P2)
    }
    if (tid < VN) nmL[tid] = node_mask[b * VN + tid];
    __syncthreads();
    // ---- P1b: node-feature slot gather (96 edges x 16 float4 slots) + compact in-edge scatter ----
    for (int idx = tid; idx < EMAX * 16; idx += NT) {
        int le = idx >> 4, seg = idx & 15;
        float4 v4 = make_float4(0.f, 0.f, 0.f, 0.f);
        if (le < nE) {
            int node = (seg < 8) ? nodeL[le] : nbL[le];
            v4 = *(const float4*)&nodes[((size_t)b * VN + node) * NF + (seg & 7) * 4];
        }
        unsigned* dst = (unsigned*)&eIn[le * WPSTR + ((seg < 8) ? 0 : 32) + (seg & 7) * 4];
        dst[0] = packbf(v4.x, v4.y);
        dst[1] = packbf(v4.z, v4.w);
    }
    {
        int k0 = eoff[s0], k1 = eoff[s1];
        for (int k = k0 + tid; k < k1; k += NT) {
            int le = igeb[k] - s0;
            int pos = atomicAdd(&degL[le], 1);   // order-independent sum downstream
            srcL[le * DMAX + pos] = ieb[k] - s0;
        }
    }
    __syncthreads();
    // ---- P2: e_emb = tanh(e_in @ Wpt + b_pre); col-tile c = wave, phase-local B hoist ----
    {
        int c = wave;
        short8 Bf[3];
        #pragma unroll
        for (int kb = 0; kb < 3; ++kb)
            Bf[kb] = *(const short8*)((const short*)Wpt + (size_t)(c * 16 + lm) * WPSTR + kb * 32 + lq * 8);
        float bp = b_pre[c * 16 + lm];
        int col = c * 16 + lm;
        for (int r = 0; r < 6; ++r) {
            short8 Af[3];
            #pragma unroll
            for (int kb = 0; kb < 3; ++kb)
                Af[kb] = *(const short8*)((const short*)eIn + (r * 16 + lm) * WPSTR + kb * 32 + lq * 8);
            f32x4 acc = {0.f, 0.f, 0.f, 0.f};
            #pragma unroll
            for (int kb = 0; kb < 3; ++kb)
                acc = __builtin_amdgcn_mfma_f32_16x16x32_bf16(Af[kb], Bf[kb], acc, 0, 0, 0);
            #pragma unroll
            for (int i = 0; i < 4; ++i)
                eL[(r * 16 + lq * 4 + i) * MSTR + col] = __float2bfloat16(fast_tanh(acc[i] + bp));
        }
    }
    __syncthreads();
    // ---- P3: beL = exp(2*(e_emb @ Wt1 + b_emb)); phase-local B hoist; writes beL only ----
    {
        int c = wave;
        short8 Bf[4];
        #pragma unroll
        for (int kb = 0; kb < 4; ++kb)
            Bf[kb] = *(const short8*)((const short*)Wt1 + (size_t)(c * 16 + lm) * 128 + kb * 32 + lq * 8);
        float bv = b_emb[c * 16 + lm];
        int col = c * 16 + lm;
        for (int r = 0; r < 6; ++r) {
            short8 Af[4];
            #pragma unroll
            for (int kb = 0; kb < 4; ++kb)
                Af[kb] = *(const short8*)((const short*)eL + (r * 16 + lm) * MSTR + kb * 32 + lq * 8);
            f32x4 acc = {0.f, 0.f, 0.f, 0.f};
            #pragma unroll
            for (int kb = 0; kb < 4; ++kb)
                acc = __builtin_amdgcn_mfma_f32_16x16x32_bf16(Af[kb], Bf[kb], acc, 0, 0, 0);
            #pragma unroll
            for (int i = 0; i < 4; ++i)
                beL[(r * 16 + lq * 4 + i) * 128 + col] =
                    __float2bfloat16(__expf(2.f * (acc[i] + bv)));
        }
    }
    __syncthreads();
    // ---- P4: eL dead -> memL = tanh(be) from beL (packed); hoist per-edge e2b into regs ----
    unsigned e2bP[EPW];
    #pragma unroll
    for (int i = 0; i < EPW; ++i) {
        int le = wave + i * NW;
        unsigned lo = beLu[le * 128 + lane];
        unsigned hi = beLu[le * 128 + 64 + lane];
        e2bP[i] = (hi << 16) | lo;
    }
    for (int idx = tid; idx < EMAX * 64; idx += NT) {
        int le = idx >> 6, cp = idx & 63;
        unsigned pk = 0;
        if (le < nE) {
            unsigned w = beLw[le * 64 + cp];
            float e0 = __uint_as_float(w << 16);
            float e1 = __uint_as_float(w & 0xFFFF0000u);
            float v0 = fmaf(-2.f, __builtin_amdgcn_rcpf(e0 + 1.f), 1.f);
            float v1 = fmaf(-2.f, __builtin_amdgcn_rcpf(e1 + 1.f), 1.f);
            pk = (bf16b(v1) << 16) | bf16b(v0);
        }
        *(unsigned*)((unsigned short*)memL + le * MSTR + cp * 2) = pk;
    }
    __syncthreads();

    for (int step = 0; step < 2; ++step) {
        // Mae: paired att/emb tiles; B-frags hoisted PER STEP (dead before msg loop)
        {
            short8 BfA[4], BfE[4];
            int c = wave;
            #pragma unroll
            for (int kb = 0; kb < 4; ++kb) {
                BfA[kb] = *(const short8*)((const short*)Wt2 + (size_t)(c * 16 + lm) * 128 + kb * 32 + lq * 8);
                BfE[kb] = *(const short8*)((const short*)Wt2 + (size_t)(128 + c * 16 + lm) * 128 + kb * 32 + lq * 8);
            }
            int col = c * 16 + lm;
            for (int r = 0; r < 6; ++r) {
                short8 Af[4];
                #pragma unroll
                for (int kb = 0; kb < 4; ++kb)
                    Af[kb] = *(const short8*)((const short*)memL + (r * 16 + lm) * MSTR + kb * 32 + lq * 8);
                f32x4 aa = {0.f, 0.f, 0.f, 0.f};
                #pragma unroll
                for (int kb = 0; kb < 4; ++kb)
                    aa = __builtin_amdgcn_mfma_f32_16x16x32_bf16(Af[kb], BfA[kb], aa, 0, 0, 0);
                f32x4 ae = {0.f, 0.f, 0.f, 0.f};
                #pragma unroll
                for (int kb = 0; kb < 4; ++kb)
                    ae = __builtin_amdgcn_mfma_f32_16x16x32_bf16(Af[kb], BfE[kb], ae, 0, 0, 0);
                int row0 = r * 16 + lq * 4;
                #pragma unroll
                for (int i = 0; i < 4; ++i)
                    MaMeL[(row0 + i) * 128 + col] =
                        (bf16b(__expf(2.f * ae[i])) << 16) | bf16b(__expf(aa[i]));
            }
        }
        __syncthreads();
        if (step == 1) {       // memL dead; zero nsF (same LDS) before scatter
            for (int idx = tid; idx < VN * 128; idx += NT) nsF[idx] = 0.f;
            __syncthreads();
        }
        // msg: wave-per-edge; compacted deg loop; e2b from regs (no global reads)
        #pragma unroll
        for (int i = 0; i < EPW; ++i) {
            int le = wave + i * NW;
            if (le < nE) {
                int deg = __builtin_amdgcn_readfirstlane(degL[le]);
                int sv = srcL[le * DMAX + (lane & 7)];
                unsigned pkb = e2bP[i];
                float e2b0 = __uint_as_float(pkb << 16);
                float e2b1 = __uint_as_float(pkb & 0xFFFF0000u);
                float sw0 = 0.f, swr0 = 0.f, sw1 = 0.f, swr1 = 0.f;
                for (int d = 0; d < deg; ++d) {
                    int ls = __builtin_amdgcn_readlane(sv, d);
                    unsigned pk0 = MaMeL[ls * 128 + lane];
                    unsigned pk1 = MaMeL[ls * 128 + 64 + lane];
                    float w0 = __uint_as_float(pk0 << 16);
                    float m0 = __uint_as_float(pk0 & 0xFFFF0000u);
                    float w1 = __uint_as_float(pk1 << 16);
                    float m1 = __uint_as_float(pk1 & 0xFFFF0000u);
                    sw0 += w0;
                    swr0 = fmaf(w0, __builtin_amdgcn_rcpf(fmaf(e2b0, m0, 1.f)), swr0);
                    sw1 += w1;
                    swr1 = fmaf(w1, __builtin_amdgcn_rcpf(fmaf(e2b1, m1, 1.f)), swr1);
                }
                float r0 = deg ? swr0 * __builtin_amdgcn_rcpf(sw0)
                               : __builtin_amdgcn_rcpf(e2b0 + 1.f);
                float r1 = deg ? swr1 * __builtin_amdgcn_rcpf(sw1)
                               : __builtin_amdgcn_rcpf(e2b1 + 1.f);
                float v0 = fmaf(-2.f, r0, 1.f);
                float v1 = fmaf(-2.f, r1, 1.f);
                if (step == 0) {
                    memL[le * MSTR + lane] = __float2bfloat16(v0);
                    memL[le * MSTR + 64 + lane] = __float2bfloat16(v1);
                } else {       // final step: scatter straight into node sums
                    int v = __builtin_amdgcn_readfirstlane(nodeL[le]);
                    atomicAdd(&nsF[v * 128 + lane], v0);
                    atomicAdd(&nsF[v * 128 + 64 + lane], v1);
                }
            }
        }
        __syncthreads();
    }

    // nsF -> bf16 nsbL (pads zero), packed u32 writes
    for (int idx = tid; idx < 48 * 64; idx += NT) {
        int v = idx >> 6, kp = idx & 63;
        unsigned pk = 0;
        if (v < VN) pk = packbf(nsF[v * 128 + kp * 2], nsF[v * 128 + kp * 2 + 1]);
        *(unsigned*)((unsigned short*)nsbL + v * MSTR + kp * 2) = pk;
    }
    __syncthreads();
    // GO = nsb @ Wt3 + bias : 2 col-tiles per wave, phase-local hoisted B-frags
    {
        int c0 = wave * 2, c1 = wave * 2 + 1;
        short8 Bg0[4], Bg1[4];
        #pragma unroll
        for (int kb = 0; kb < 4; ++kb) {
            Bg0[kb] = *(const short8*)((const short*)Wt3 + (size_t)(c0 * 16 + lm) * 128 + kb * 32 + lq * 8);
            Bg1[kb] = *(const short8*)((const short*)Wt3 + (size_t)(c1 * 16 + lm) * 128 + kb * 32 + lq * 8);
        }
        int col0 = c0 * 16 + lm, col1 = c1 * 16 + lm;
        float bv0 = (col0 < 128) ? bg_att[col0] : bg_emb[col0 & 127];
        float bv1 = (col1 < 128) ? bg_att[col1] : bg_emb[col1 & 127];
        __hip_bfloat16* hp = (__hip_bfloat16*)GOLp;
        for (int r = 0; r < 3; ++r) {
            short8 Af[4];
            #pragma unroll
            for (int kb = 0; kb < 4; ++kb)
                Af[kb] = *(const short8*)((const short*)nsbL + (r * 16 + lm) * MSTR + kb * 32 + lq * 8);
            f32x4 a0 = {0.f, 0.f, 0.f, 0.f}, a1 = {0.f, 0.f, 0.f, 0.f};
            #pragma unroll
            for (int kb = 0; kb < 4; ++kb) {
                a0 = __builtin_amdgcn_mfma_f32_16x16x32_bf16(Af[kb], Bg0[kb], a0, 0, 0, 0);
                a1 = __builtin_amdgcn_mfma_f32_16x16x32_bf16(Af[kb], Bg1[kb], a1, 0, 0, 0);
            }
            int row0 = r * 16 + lq * 4;
            #pragma unroll
            for (int i = 0; i < 4; ++i) {
                if (col0 < 128)
                    hp[((row0 + i) * 128 + col0) * 2] = __float2bfloat16(__expf(a0[i] + bv0));
                else
                    hp[((row0 + i) * 128 + (col0 & 127)) * 2 + 1] = __float2bfloat16(__expf(2.f * (a0[i] + bv0)));
                if (col1 < 128)
                    hp[((row0 + i) * 128 + col1) * 2] = __float2bfloat16(__expf(a1[i] + bv1));
                else
                    hp[((row0 + i) * 128 + (col1 & 127)) * 2 + 1] = __float2bfloat16(__expf(2.f * (a1[i] + bv1)));
            }
        }
    }
    __syncthreads();
    // node softmax: 4-way v-split; gemb = 1 - 2*Σ(w*r)/Σw
    {
        int c = tid & 127, q = tid >> 7;      // q in 0..3
        float sw = 0.f, swr = 0.f;
        for (int v = q; v < VN; v += 4) {
            if (nmL[v] == 0.f) continue;
            unsigned pk = GOLp[v * 128 + c];
            float w = __uint_as_float(pk << 16);
            float e2 = __uint_as_float(pk & 0xFFFF0000u);
            sw += w;
            swr = fmaf(w, __builtin_amdgcn_rcpf(e2 + 1.f), swr);
        }
        numP[tid] = swr;
        denP[tid] = sw;
    }
    __syncthreads();
    if (tid < 128) {
        float swr = 0.f, sw = 0.f;
        #pragma unroll
        for (int p = 0; p < 4; ++p) { swr += numP[p * 128 + tid]; sw += denP[p * 128 + tid]; }
        gembL[tid] = fmaf(-2.f, swr / sw, 1.f);
    }
    __syncthreads();
    // out = gemb @ W_out + b_out (4-way j-split)
    {
        int c = tid & 127, h = tid >> 7;      // h in 0..3
        float acc = 0.f;
        for (int j = h; j < 128; j += 4)
            acc += gembL[j] * W_out[j * OUTD + c];
        redL[tid] = acc;
    }
    __syncthreads();
    if (tid < 128) {
        float acc = b_out[tid];
        #pragma unroll
        for (int p = 0; p < 4; ++p) acc += redL[p * 128 + tid];
        out[(size_t)b * OUTD + tid] = acc;
    }
}

extern "C" void kernel_launch(void* const* d_in, const int* in_sizes, int n_in,
                              void* d_out, int out_size, void* d_ws, size_t ws_size,
                              hipStream_t stream) {
    const float* nodes    = (const float*)d_in[0];
    const float* edges    = (const float*)d_in[1];
    const float* W_pre    = (const float*)d_in[2];
    const float* b_pre    = (const float*)d_in[3];
    const float* W_att    = (const float*)d_in[4];
    const float* W_emb    = (const float*)d_in[6];
    const float* b_emb    = (const float*)d_in[7];
    const float* Wg_att   = (const float*)d_in[8];
    const float* bg_att   = (const float*)d_in[9];
    const float* Wg_emb   = (const float*)d_in[10];
    const float* bg_emb   = (const float*)d_in[11];
    const float* W_out    = (const float*)d_in[12];
    const float* b_out    = (const float*)d_in[13];
    const float* node_mask = (const float*)d_in[15];
    const int* eb_b   = (const int*)d_in[16];
    const int* eb_n   = (const int*)d_in[17];
    const int* eb_nb  = (const int*)d_in[18];
    const int* in_eb  = (const int*)d_in[19];
    const int* in_igeb = (const int*)d_in[20];

    int E = in_sizes[16];
    int K = in_sizes[19];

    __hip_bfloat16* Wt1 = (__hip_bfloat16*)d_ws;              // 128*128
    __hip_bfloat16* Wt2 = Wt1 + 128 * 128;                    // 256*128
    __hip_bfloat16* Wt3 = Wt2 + 256 * 128;                    // 256*128
    __hip_bfloat16* Wpt = Wt3 + 256 * 128;                    // 128*WPSTR
    int* off  = (int*)(Wpt + 128 * WPSTR);                    // NN+1
    int* eoff = off + (NN + 1);                               // E+1

    int nbO = (E + 255) / 256;
    int nbK = (K + 255) / 256;

    k_setup<<<nbO + nbK + 128, 256, 0, stream>>>(in_igeb, eb_b,
                                                 W_att, W_emb, Wg_att, Wg_emb, W_pre,
                                                 off, eoff, Wt1, Wt2, Wt3, Wpt,
                                                 K, E, nbO, nbK);
    k_mp<<<NN, NT, 0, stream>>>(nodes, edges, Wpt, b_pre, Wt1, b_emb,
                                Wt2, Wt3, bg_att, bg_emb,
                                in_igeb, in_eb, eoff, eb_n, eb_nb, node_mask,
                                W_out, b_out, off, (float*)d_out);
}

// Round 6
// 176.867 us; speedup vs baseline: 1.0512x; 1.0009x over previous
//
#include <hip/hip_runtime.h>
#include <hip/hip_bf16.h>
#include <math.h>

#define NN 512
#define VN 40
#define NF 32
#define EFD 4
#define OUTD 128
#define EMAX 96     // max directed edges per graph (<= 90 actual)
#define DMAX 8      // max in-degree
#define MSTR 136    // LDS row stride (shorts) for 128-wide MFMA A-operands
#define WPSTR 104   // row stride (shorts) for 96-wide (68-padded) operands
#define NT 512      // k_mp threads (8 waves)
#define NW 8
#define EPW 12      // edges per wave (EMAX/NW)

typedef __attribute__((ext_vector_type(8))) short short8;
typedef __attribute__((ext_vector_type(4))) float f32x4;

// tanh(x) = 1 - 2/(exp(2x)+1)
__device__ __forceinline__ float fast_tanh(float x) {
    return fmaf(-2.0f, __builtin_amdgcn_rcpf(__expf(2.0f * x) + 1.0f), 1.0f);
}
__device__ __forceinline__ unsigned bf16b(float x) {
    __hip_bfloat16 h = __float2bfloat16(x);
    unsigned short u;
    __builtin_memcpy(&u, &h, 2);
    return (unsigned)u;
}
__device__ __forceinline__ unsigned packbf(float lo, float hi) {
    return (bf16b(hi) << 16) | bf16b(lo);
}

// Setup: [0,nbO): off boundaries | [nbO,+nbK): eoff boundaries | [+128): weight conv
__global__ __launch_bounds__(256) void k_setup(
    const int* __restrict__ igeb, const int* __restrict__ eb_b,
    const float* __restrict__ W_att, const float* __restrict__ W_emb,
    const float* __restrict__ Wg_att, const float* __restrict__ Wg_emb,
    const float* __restrict__ W_pre,
    int* __restrict__ off, int* __restrict__ eoff,
    __hip_bfloat16* __restrict__ Wt1, __hip_bfloat16* __restrict__ Wt2,
    __hip_bfloat16* __restrict__ Wt3, __hip_bfloat16* __restrict__ Wpt,
    int K, int E, int nbO, int nbK)
{
    int bid = blockIdx.x, tid = threadIdx.x;
    if (bid < nbO) {                       // per-graph edge offsets (eb_b sorted)
        int e = bid * 256 + tid;
        if (e >= E) return;
        int b = eb_b[e];
        if (e == 0) { for (int bb = 0; bb <= b; ++bb) off[bb] = 0; }
        else { int pb = eb_b[e - 1]; for (int bb = pb + 1; bb <= b; ++bb) off[bb] = e; }
        if (e == E - 1) { for (int bb = b + 1; bb <= NN; ++bb) off[bb] = E; }
        return;
    }
    bid -= nbO;
    if (bid < nbK) {                       // per-edge K-offsets (igeb sorted)
        int k = bid * 256 + tid;
        if (k >= K) return;
        int e = igeb[k];
        if (k == 0) { for (int ee = 0; ee <= e; ++ee) eoff[ee] = 0; }
        else { int pe = igeb[k - 1]; for (int ee = pe + 1; ee <= e; ++ee) eoff[ee] = k; }
        if (k == K - 1) { for (int ee = e + 1; ee <= E; ++ee) eoff[ee] = K; }
        return;
    }
    bid -= nbK;
    // weight transpose/convert (2 output-cols per block)
    int c = bid * 2 + (tid >> 7), k = tid & 127;
    int cc = c & 127; bool hi = c >= 128;
    if (!hi) {                             // emb-top half only (att-top cancels in softmax)
        Wt1[c * 128 + k] = __float2bfloat16(W_emb[k * 128 + c]);
        if (k < WPSTR)
            Wpt[c * WPSTR + k] = __float2bfloat16(k < 68 ? W_pre[k * 128 + c] : 0.f);
    }
    Wt2[c * 128 + k] = __float2bfloat16(hi ? W_emb[(128 + k) * 128 + cc] : W_att[(128 + k) * 128 + cc]);
    Wt3[c * 128 + k] = __float2bfloat16(hi ? Wg_emb[k * 128 + cc]
                                           : (Wg_att[k * 128 + cc] + Wg_att[(128 + k) * 128 + cc]));
}

// Fully-fused per-graph pre + MP + readout. 512 threads (8 waves), ~80 KB LDS, 2 blocks/CU.
// waves_per_eu(4,4): LDS caps us at 2 blocks/CU = 4 waves/EU anyway; pinning min=max
// stops the allocator from chasing 8 waves/EU (VGPR<=64) and spilling ~11 MB to scratch.
__global__ __attribute__((amdgpu_flat_work_group_size(NT, NT), amdgpu_waves_per_eu(4, 4)))
void k_mp(
    const float* __restrict__ nodes, const float* __restrict__ edges,
    const __hip_bfloat16* __restrict__ Wpt, const float* __restrict__ b_pre,
    const __hip_bfloat16* __restrict__ Wt1, const float* __restrict__ b_emb,
    const __hip_bfloat16* __restrict__ Wt2, const __hip_bfloat16* __restrict__ Wt3,
    const float* __restrict__ bg_att, const float* __restrict__ bg_emb,
    const int* __restrict__ igeb, const int* __restrict__ ieb,
    const int* __restrict__ eoff,
    const int* __restrict__ eb_n, const int* __restrict__ eb_nb,
    const float* __restrict__ node_mask,
    const float* __restrict__ W_out, const float* __restrict__ b_out,
    const int* __restrict__ off, float* __restrict__ out)
{
    __shared__ __align__(16) char pool[75264];
    __shared__ float gembL[128];
    __shared__ float nmL[VN];
    __shared__ int srcL[EMAX * DMAX];    // compacted LOCAL source indices
    __shared__ int degL[EMAX];           // per-edge in-degree
    __shared__ int nodeL[EMAX];
    __shared__ int nbL[EMAX];
    // Phase-aliased pool regions (all transitions barrier-separated):
    __hip_bfloat16* eIn  = (__hip_bfloat16*)(pool + 26112);   // [96][WPSTR] prologue only
    __hip_bfloat16* eL   = (__hip_bfloat16*)pool;             // [96][MSTR]  e_emb
    __hip_bfloat16* beL  = (__hip_bfloat16*)(pool + 26112);   // [96][128]   exp(2*be) (over dead eIn)
    const unsigned short* beLu = (const unsigned short*)(pool + 26112);
    const unsigned* beLw = (const unsigned*)(pool + 26112);   // paired view
    __hip_bfloat16* memL = (__hip_bfloat16*)pool;             // [96][MSTR]  (over dead eL, written AFTER P3 barrier)
    unsigned*       MaMeL = (unsigned*)(pool + 26112);        // [96][128] lo=bf16(exp(Ma)) hi=bf16(exp(2Me))
    float*          nsF   = (float*)pool;                     // [40][128] (over memL after Mae step1)
    __hip_bfloat16* nsbL  = (__hip_bfloat16*)(pool + 26112);  // [48][MSTR]
    unsigned*       GOLp  = (unsigned*)(pool + 39168);        // [48][128] packed exp
    float*          numP  = (float*)pool;                     // [NT] (post-GO, over memL)
    float*          denP  = (float*)(pool + 2048);            // [NT]
    float*          redL  = (float*)(pool + 4096);            // [NT]

    int b = blockIdx.x;
    int s0 = off[b], s1 = off[b + 1];
    int nE = s1 - s0;
    int tid = threadIdx.x;
    int wave = tid >> 6, lane = tid & 63, lm = lane & 15, lq = lane >> 4;

    // ---- P1a: per-edge meta, edge features, pad cols; node mask ----
    if (tid < EMAX) {
        degL[tid] = 0;
        bool vld = tid < nE;
        int n = 0, nb = 0;
        if (vld) { n = eb_n[s0 + tid]; nb = eb_nb[s0 + tid]; }
        nodeL[tid] = n; nbL[tid] = nb;
        float4 ev = make_float4(0.f, 0.f, 0.f, 0.f);
        if (vld) ev = *(const float4*)&edges[(((size_t)b * VN + n) * VN + nb) * EFD];
        unsigned* dst = (unsigned*)&eIn[tid * WPSTR + 64];   // byte off tid*208+128, 16B aligned
        dst[0] = packbf(ev.x, ev.y);
        dst[1] = packbf(ev.z, ev.w);
        #pragma unroll
        for (int f = 0; f < 14; ++f) dst[2 + f] = 0u;        // shorts 68..96 zero (K=96 for P2)
    }
    if (tid < VN) nmL[tid] = node_mask[b * VN + tid];
    __syncthreads();
    // ---- P1b: node-feature slot gather (96 edges x 16 float4 slots) + compact in-edge scatter ----
    for (int idx = tid; idx < EMAX * 16; idx += NT) {
        int le = idx >> 4, seg = idx & 15;
        float4 v4 = make_float4(0.f, 0.f, 0.f, 0.f);
        if (le < nE) {
            int node = (seg < 8) ? nodeL[le] : nbL[le];
            v4 = *(const float4*)&nodes[((size_t)b * VN + node) * NF + (seg & 7) * 4];
        }
        unsigned* dst = (unsigned*)&eIn[le * WPSTR + ((seg < 8) ? 0 : 32) + (seg & 7) * 4];
        dst[0] = packbf(v4.x, v4.y);
        dst[1] = packbf(v4.z, v4.w);
    }
    {
        int k0 = eoff[s0], k1 = eoff[s1];
        for (int k = k0 + tid; k < k1; k += NT) {
            int le = igeb[k] - s0;
            int pos = atomicAdd(&degL[le], 1);   // order-independent sum downstream
            srcL[le * DMAX + pos] = ieb[k] - s0;
        }
    }
    __syncthreads();
    // ---- P2: e_emb = tanh(e_in @ Wpt + b_pre); col-tile c = wave, phase-local B hoist ----
    {
        int c = wave;
        short8 Bf[3];
        #pragma unroll
        for (int kb = 0; kb < 3; ++kb)
            Bf[kb] = *(const short8*)((const short*)Wpt + (size_t)(c * 16 + lm) * WPSTR + kb * 32 + lq * 8);
        float bp = b_pre[c * 16 + lm];
        int col = c * 16 + lm;
        for (int r = 0; r < 6; ++r) {
            short8 Af[3];
            #pragma unroll
            for (int kb = 0; kb < 3; ++kb)
                Af[kb] = *(const short8*)((const short*)eIn + (r * 16 + lm) * WPSTR + kb * 32 + lq * 8);
            f32x4 acc = {0.f, 0.f, 0.f, 0.f};
            #pragma unroll
            for (int kb = 0; kb < 3; ++kb)
                acc = __builtin_amdgcn_mfma_f32_16x16x32_bf16(Af[kb], Bf[kb], acc, 0, 0, 0);
            #pragma unroll
            for (int i = 0; i < 4; ++i)
                eL[(r * 16 + lq * 4 + i) * MSTR + col] = __float2bfloat16(fast_tanh(acc[i] + bp));
        }
    }
    __syncthreads();
    // ---- P3: beL = exp(2*(e_emb @ Wt1 + b_emb)); phase-local B hoist; writes beL only ----
    {
        int c = wave;
        short8 Bf[4];
        #pragma unroll
        for (int kb = 0; kb < 4; ++kb)
            Bf[kb] = *(const short8*)((const short*)Wt1 + (size_t)(c * 16 + lm) * 128 + kb * 32 + lq * 8);
        float bv = b_emb[c * 16 + lm];
        int col = c * 16 + lm;
        for (int r = 0; r < 6; ++r) {
            short8 Af[4];
            #pragma unroll
            for (int kb = 0; kb < 4; ++kb)
                Af[kb] = *(const short8*)((const short*)eL + (r * 16 + lm) * MSTR + kb * 32 + lq * 8);
            f32x4 acc = {0.f, 0.f, 0.f, 0.f};
            #pragma unroll
            for (int kb = 0; kb < 4; ++kb)
                acc = __builtin_amdgcn_mfma_f32_16x16x32_bf16(Af[kb], Bf[kb], acc, 0, 0, 0);
            #pragma unroll
            for (int i = 0; i < 4; ++i)
                beL[(r * 16 + lq * 4 + i) * 128 + col] =
                    __float2bfloat16(__expf(2.f * (acc[i] + bv)));
        }
    }
    __syncthreads();
    // ---- P4: eL dead -> memL = tanh(be) from beL (packed); hoist per-edge e2b into regs ----
    unsigned e2bP[EPW];
    #pragma unroll
    for (int i = 0; i < EPW; ++i) {
        int le = wave + i * NW;
        unsigned lo = beLu[le * 128 + lane];
        unsigned hi = beLu[le * 128 + 64 + lane];
        e2bP[i] = (hi << 16) | lo;
    }
    for (int idx = tid; idx < EMAX * 64; idx += NT) {
        int le = idx >> 6, cp = idx & 63;
        unsigned pk = 0;
        if (le < nE) {
            unsigned w = beLw[le * 64 + cp];
            float e0 = __uint_as_float(w << 16);
            float e1 = __uint_as_float(w & 0xFFFF0000u);
            float v0 = fmaf(-2.f, __builtin_amdgcn_rcpf(e0 + 1.f), 1.f);
            float v1 = fmaf(-2.f, __builtin_amdgcn_rcpf(e1 + 1.f), 1.f);
            pk = (bf16b(v1) << 16) | bf16b(v0);
        }
        *(unsigned*)((unsigned short*)memL + le * MSTR + cp * 2) = pk;
    }
    __syncthreads();

    for (int step = 0; step < 2; ++step) {
        // Mae: paired att/emb tiles; B-frags hoisted PER STEP (dead before msg loop)
        {
            short8 BfA[4], BfE[4];
            int c = wave;
            #pragma unroll
            for (int kb = 0; kb < 4; ++kb) {
                BfA[kb] = *(const short8*)((const short*)Wt2 + (size_t)(c * 16 + lm) * 128 + kb * 32 + lq * 8);
                BfE[kb] = *(const short8*)((const short*)Wt2 + (size_t)(128 + c * 16 + lm) * 128 + kb * 32 + lq * 8);
            }
            int col = c * 16 + lm;
            for (int r = 0; r < 6; ++r) {
                short8 Af[4];
                #pragma unroll
                for (int kb = 0; kb < 4; ++kb)
                    Af[kb] = *(const short8*)((const short*)memL + (r * 16 + lm) * MSTR + kb * 32 + lq * 8);
                f32x4 aa = {0.f, 0.f, 0.f, 0.f};
                #pragma unroll
                for (int kb = 0; kb < 4; ++kb)
                    aa = __builtin_amdgcn_mfma_f32_16x16x32_bf16(Af[kb], BfA[kb], aa, 0, 0, 0);
                f32x4 ae = {0.f, 0.f, 0.f, 0.f};
                #pragma unroll
                for (int kb = 0; kb < 4; ++kb)
                    ae = __builtin_amdgcn_mfma_f32_16x16x32_bf16(Af[kb], BfE[kb], ae, 0, 0, 0);
                int row0 = r * 16 + lq * 4;
                #pragma unroll
                for (int i = 0; i < 4; ++i)
                    MaMeL[(row0 + i) * 128 + col] =
                        (bf16b(__expf(2.f * ae[i])) << 16) | bf16b(__expf(aa[i]));
            }
        }
        __syncthreads();
        if (step == 1) {       // memL dead; zero nsF (same LDS) before scatter
            for (int idx = tid; idx < VN * 128; idx += NT) nsF[idx] = 0.f;
            __syncthreads();
        }
        // msg: wave-per-edge; compacted deg loop; e2b from regs (no global reads)
        #pragma unroll
        for (int i = 0; i < EPW; ++i) {
            int le = wave + i * NW;
            if (le < nE) {
                int deg = __builtin_amdgcn_readfirstlane(degL[le]);
                int sv = srcL[le * DMAX + (lane & 7)];
                unsigned pkb = e2bP[i];
                float e2b0 = __uint_as_float(pkb << 16);
                float e2b1 = __uint_as_float(pkb & 0xFFFF0000u);
                float sw0 = 0.f, swr0 = 0.f, sw1 = 0.f, swr1 = 0.f;
                for (int d = 0; d < deg; ++d) {
                    int ls = __builtin_amdgcn_readlane(sv, d);
                    unsigned pk0 = MaMeL[ls * 128 + lane];
                    unsigned pk1 = MaMeL[ls * 128 + 64 + lane];
                    float w0 = __uint_as_float(pk0 << 16);
                    float m0 = __uint_as_float(pk0 & 0xFFFF0000u);
                    float w1 = __uint_as_float(pk1 << 16);
                    float m1 = __uint_as_float(pk1 & 0xFFFF0000u);
                    sw0 += w0;
                    swr0 = fmaf(w0, __builtin_amdgcn_rcpf(fmaf(e2b0, m0, 1.f)), swr0);
                    sw1 += w1;
                    swr1 = fmaf(w1, __builtin_amdgcn_rcpf(fmaf(e2b1, m1, 1.f)), swr1);
                }
                float r0 = deg ? swr0 * __builtin_amdgcn_rcpf(sw0)
                               : __builtin_amdgcn_rcpf(e2b0 + 1.f);
                float r1 = deg ? swr1 * __builtin_amdgcn_rcpf(sw1)
                               : __builtin_amdgcn_rcpf(e2b1 + 1.f);
                float v0 = fmaf(-2.f, r0, 1.f);
                float v1 = fmaf(-2.f, r1, 1.f);
                if (step == 0) {
                    memL[le * MSTR + lane] = __float2bfloat16(v0);
                    memL[le * MSTR + 64 + lane] = __float2bfloat16(v1);
                } else {       // final step: scatter straight into node sums
                    int v = __builtin_amdgcn_readfirstlane(nodeL[le]);
                    atomicAdd(&nsF[v * 128 + lane], v0);
                    atomicAdd(&nsF[v * 128 + 64 + lane], v1);
                }
            }
        }
        __syncthreads();
    }

    // nsF -> bf16 nsbL (pads zero), packed u32 writes
    for (int idx = tid; idx < 48 * 64; idx += NT) {
        int v = idx >> 6, kp = idx & 63;
        unsigned pk = 0;
        if (v < VN) pk = packbf(nsF[v * 128 + kp * 2], nsF[v * 128 + kp * 2 + 1]);
        *(unsigned*)((unsigned short*)nsbL + v * MSTR + kp * 2) = pk;
    }
    __syncthreads();
    // GO = nsb @ Wt3 + bias : 2 col-tiles per wave, phase-local hoisted B-frags
    {
        int c0 = wave * 2, c1 = wave * 2 + 1;
        short8 Bg0[4], Bg1[4];
        #pragma unroll
        for (int kb = 0; kb < 4; ++kb) {
            Bg0[kb] = *(const short8*)((const short*)Wt3 + (size_t)(c0 * 16 + lm) * 128 + kb * 32 + lq * 8);
            Bg1[kb] = *(const short8*)((const short*)Wt3 + (size_t)(c1 * 16 + lm) * 128 + kb * 32 + lq * 8);
        }
        int col0 = c0 * 16 + lm, col1 = c1 * 16 + lm;
        float bv0 = (col0 < 128) ? bg_att[col0] : bg_emb[col0 & 127];
        float bv1 = (col1 < 128) ? bg_att[col1] : bg_emb[col1 & 127];
        __hip_bfloat16* hp = (__hip_bfloat16*)GOLp;
        for (int r = 0; r < 3; ++r) {
            short8 Af[4];
            #pragma unroll
            for (int kb = 0; kb < 4; ++kb)
                Af[kb] = *(const short8*)((const short*)nsbL + (r * 16 + lm) * MSTR + kb * 32 + lq * 8);
            f32x4 a0 = {0.f, 0.f, 0.f, 0.f}, a1 = {0.f, 0.f, 0.f, 0.f};
            #pragma unroll
            for (int kb = 0; kb < 4; ++kb) {
                a0 = __builtin_amdgcn_mfma_f32_16x16x32_bf16(Af[kb], Bg0[kb], a0, 0, 0, 0);
                a1 = __builtin_amdgcn_mfma_f32_16x16x32_bf16(Af[kb], Bg1[kb], a1, 0, 0, 0);
            }
            int row0 = r * 16 + lq * 4;
            #pragma unroll
            for (int i = 0; i < 4; ++i) {
                if (col0 < 128)
                    hp[((row0 + i) * 128 + col0) * 2] = __float2bfloat16(__expf(a0[i] + bv0));
                else
                    hp[((row0 + i) * 128 + (col0 & 127)) * 2 + 1] = __float2bfloat16(__expf(2.f * (a0[i] + bv0)));
                if (col1 < 128)
                    hp[((row0 + i) * 128 + col1) * 2] = __float2bfloat16(__expf(a1[i] + bv1));
                else
                    hp[((row0 + i) * 128 + (col1 & 127)) * 2 + 1] = __float2bfloat16(__expf(2.f * (a1[i] + bv1)));
            }
        }
    }
    __syncthreads();
    // node softmax: 4-way v-split; gemb = 1 - 2*Σ(w*r)/Σw
    {
        int c = tid & 127, q = tid >> 7;      // q in 0..3
        float sw = 0.f, swr = 0.f;
        for (int v = q; v < VN; v += 4) {
            if (nmL[v] == 0.f) continue;
            unsigned pk = GOLp[v * 128 + c];
            float w = __uint_as_float(pk << 16);
            float e2 = __uint_as_float(pk & 0xFFFF0000u);
            sw += w;
            swr = fmaf(w, __builtin_amdgcn_rcpf(e2 + 1.f), swr);
        }
        numP[tid] = swr;
        denP[tid] = sw;
    }
    __syncthreads();
    if (tid < 128) {
        float swr = 0.f, sw = 0.f;
        #pragma unroll
        for (int p = 0; p < 4; ++p) { swr += numP[p * 128 + tid]; sw += denP[p * 128 + tid]; }
        gembL[tid] = fmaf(-2.f, swr / sw, 1.f);
    }
    __syncthreads();
    // out = gemb @ W_out + b_out (4-way j-split)
    {
        int c = tid & 127, h = tid >> 7;      // h in 0..3
        float acc = 0.f;
        for (int j = h; j < 128; j += 4)
            acc += gembL[j] * W_out[j * OUTD + c];
        redL[tid] = acc;
    }
    __syncthreads();
    if (tid < 128) {
        float acc = b_out[tid];
        #pragma unroll
        for (int p = 0; p < 4; ++p) acc += redL[p * 128 + tid];
        out[(size_t)b * OUTD + tid] = acc;
    }
}

extern "C" void kernel_launch(void* const* d_in, const int* in_sizes, int n_in,
                              void* d_out, int out_size, void* d_ws, size_t ws_size,
                              hipStream_t stream) {
    const float* nodes    = (const float*)d_in[0];
    const float* edges    = (const float*)d_in[1];
    const float* W_pre    = (const float*)d_in[2];
    const float* b_pre    = (const float*)d_in[3];
    const float* W_att    = (const float*)d_in[4];
    const float* W_emb    = (const float*)d_in[6];
    const float* b_emb    = (const float*)d_in[7];
    const float* Wg_att   = (const float*)d_in[8];
    const float* bg_att   = (const float*)d_in[9];
    const float* Wg_emb   = (const float*)d_in[10];
    const float* bg_emb   = (const float*)d_in[11];
    const float* W_out    = (const float*)d_in[12];
    const float* b_out    = (const float*)d_in[13];
    const float* node_mask = (const float*)d_in[15];
    const int* eb_b   = (const int*)d_in[16];
    const int* eb_n   = (const int*)d_in[17];
    const int* eb_nb  = (const int*)d_in[18];
    const int* in_eb  = (const int*)d_in[19];
    const int* in_igeb = (const int*)d_in[20];

    int E = in_sizes[16];
    int K = in_sizes[19];

    __hip_bfloat16* Wt1 = (__hip_bfloat16*)d_ws;              // 128*128
    __hip_bfloat16* Wt2 = Wt1 + 128 * 128;                    // 256*128
    __hip_bfloat16* Wt3 = Wt2 + 256 * 128;                    // 256*128
    __hip_bfloat16* Wpt = Wt3 + 256 * 128;                    // 128*WPSTR
    int* off  = (int*)(Wpt + 128 * WPSTR);                    // NN+1
    int* eoff = off + (NN + 1);                               // E+1

    int nbO = (E + 255) / 256;
    int nbK = (K + 255) / 256;

    k_setup<<<nbO + nbK + 128, 256, 0, stream>>>(in_igeb, eb_b,
                                                 W_att, W_emb, Wg_att, Wg_emb, W_pre,
                                                 off, eoff, Wt1, Wt2, Wt3, Wpt,
                                                 K, E, nbO, nbK);
    k_mp<<<NN, NT, 0, stream>>>(nodes, edges, Wpt, b_pre, Wt1, b_emb,
                                Wt2, Wt3, bg_att, bg_emb,
                                in_igeb, in_eb, eoff, eb_n, eb_nb, node_mask,
                                W_out, b_out, off, (float*)d_out);
}